// Round 2
// baseline (1556.315 us; speedup 1.0000x reference)
//
#include <hip/hip_runtime.h>

#define N_NODES 50000
#define N_EDGES 800000
#define IN_F    512
#define HEADS   8
#define DHEAD   32
#define NHD     256            // HEADS*DHEAD
#define SLOPE   0.2f
#define EPS_F   1e-16f

// order-preserving float<->u32 encoding for atomicMax on floats
__device__ __forceinline__ unsigned int enc_f32(float x) {
  unsigned int u = __float_as_uint(x);
  return (u & 0x80000000u) ? ~u : (u | 0x80000000u);
}
__device__ __forceinline__ float dec_f32(unsigned int u) {
  return (u & 0x80000000u) ? __uint_as_float(u & 0x7FFFFFFFu) : __uint_as_float(~u);
}

__device__ __forceinline__ void atomAddF(float* p, float v) {
  // native global_atomic_add_f32 (atomicAdd(float*) may fall back to CAS loop)
  unsafeAtomicAdd(p, v);
}

// ---- K1: h[n][h*32+d] = sum_f x[n][f] * W[h][f][d]  (fp32 LDS-tiled GEMM)
#define BM 64
#define BN 64
#define BK 16
__global__ __launch_bounds__(256) void k_gemm(const float* __restrict__ x,
                                              const float* __restrict__ W,
                                              float* __restrict__ h) {
  __shared__ float As[BK][BM + 1];
  __shared__ float Bs[BK][BN + 1];
  const int bm = blockIdx.x * BM;
  const int bn = blockIdx.y * BN;
  const int tid = threadIdx.x;
  const int tr = tid >> 4;   // 0..15
  const int tc = tid & 15;   // 0..15
  float acc[4][4] = {{0.f}};
  for (int k0 = 0; k0 < IN_F; k0 += BK) {
#pragma unroll
    for (int i = 0; i < 4; ++i) {
      int li = tid + 256 * i;          // 0..1023
      int m = li >> 4;                 // 0..63
      int k = li & 15;
      int row = bm + m;
      As[k][m] = (row < N_NODES) ? x[(size_t)row * IN_F + k0 + k] : 0.0f;
      int kk = li >> 6;                // 0..15
      int n  = li & 63;
      int col = bn + n;                // 0..255
      Bs[kk][n] = W[(col >> 5) * (IN_F * DHEAD) + (k0 + kk) * DHEAD + (col & 31)];
    }
    __syncthreads();
#pragma unroll
    for (int k = 0; k < BK; ++k) {
      float av[4], bv[4];
#pragma unroll
      for (int i = 0; i < 4; ++i) av[i] = As[k][tr * 4 + i];
#pragma unroll
      for (int j = 0; j < 4; ++j) bv[j] = Bs[k][tc * 4 + j];
#pragma unroll
      for (int i = 0; i < 4; ++i)
#pragma unroll
        for (int j = 0; j < 4; ++j)
          acc[i][j] += av[i] * bv[j];
    }
    __syncthreads();
  }
#pragma unroll
  for (int i = 0; i < 4; ++i) {
    int row = bm + tr * 4 + i;
    if (row < N_NODES) {
#pragma unroll
      for (int j = 0; j < 4; ++j)
        h[(size_t)row * NHD + bn + tc * 4 + j] = acc[i][j];
    }
  }
}

// ---- K2: s_src[n][h] = h[n,h,:].a[h,:32]; s_dst with a[h,32:]
__global__ void k_scores(const float* __restrict__ h, const float* __restrict__ a,
                         float* __restrict__ s_src, float* __restrict__ s_dst) {
  int i = blockIdx.x * blockDim.x + threadIdx.x;
  if (i >= N_NODES * HEADS) return;
  int head = i & 7;
  int n = i >> 3;
  const float* hp = h + (size_t)n * NHD + head * DHEAD;
  const float* ap = a + head * 2 * DHEAD;
  float ss = 0.f, sd = 0.f;
#pragma unroll
  for (int d = 0; d < DHEAD; ++d) {
    float v = hp[d];
    ss += v * ap[d];
    sd += v * ap[DHEAD + d];
  }
  s_src[i] = ss;
  s_dst[i] = sd;
}

// ---- K3: segment max of leaky(logit) by e0 (encoded u32 atomicMax)
__global__ void k_edge_max(const int* __restrict__ ei,
                           const float* __restrict__ s_src, const float* __restrict__ s_dst,
                           unsigned int* __restrict__ m_enc) {
  int e = blockIdx.x * blockDim.x + threadIdx.x;
  if (e >= N_EDGES) return;
  int e0 = ei[e];
  int e1 = ei[N_EDGES + e];
  const float4* ps = (const float4*)(s_src + (size_t)e0 * 8);
  const float4* pd = (const float4*)(s_dst + (size_t)e1 * 8);
  float4 s0 = ps[0], s1 = ps[1], d0 = pd[0], d1 = pd[1];
  float lg[8] = { s0.x + d0.x, s0.y + d0.y, s0.z + d0.z, s0.w + d0.w,
                  s1.x + d1.x, s1.y + d1.y, s1.z + d1.z, s1.w + d1.w };
#pragma unroll
  for (int hh = 0; hh < 8; ++hh) {
    float v = lg[hh];
    v = v >= 0.f ? v : SLOPE * v;
    atomicMax(&m_enc[(size_t)e0 * 8 + hh], enc_f32(v));
  }
}

// ---- K4: denom[e0][h] += exp(leaky(logit) - m)
__global__ void k_edge_den(const int* __restrict__ ei,
                           const float* __restrict__ s_src, const float* __restrict__ s_dst,
                           const unsigned int* __restrict__ m_enc,
                           float* __restrict__ denom) {
  int e = blockIdx.x * blockDim.x + threadIdx.x;
  if (e >= N_EDGES) return;
  int e0 = ei[e];
  int e1 = ei[N_EDGES + e];
  const float4* ps = (const float4*)(s_src + (size_t)e0 * 8);
  const float4* pd = (const float4*)(s_dst + (size_t)e1 * 8);
  float4 s0 = ps[0], s1 = ps[1], d0 = pd[0], d1 = pd[1];
  float lg[8] = { s0.x + d0.x, s0.y + d0.y, s0.z + d0.z, s0.w + d0.w,
                  s1.x + d1.x, s1.y + d1.y, s1.z + d1.z, s1.w + d1.w };
#pragma unroll
  for (int hh = 0; hh < 8; ++hh) {
    float v = lg[hh];
    v = v >= 0.f ? v : SLOPE * v;
    float m = dec_f32(m_enc[(size_t)e0 * 8 + hh]);
    atomAddF(&denom[(size_t)e0 * 8 + hh], __expf(v - m));
  }
}

// ---- K5: out[e0][c] += alpha[head(c)] * h[e1][c], one wave per edge
__global__ __launch_bounds__(256) void k_scatter(const int* __restrict__ ei,
    const float* __restrict__ h, const float* __restrict__ s_src,
    const float* __restrict__ s_dst, const unsigned int* __restrict__ m_enc,
    const float* __restrict__ denom, float* __restrict__ out) {
  long long gt = (long long)blockIdx.x * blockDim.x + threadIdx.x;
  int e = (int)(gt >> 6);          // one 64-lane wave per edge
  int lane = threadIdx.x & 63;
  if (e >= N_EDGES) return;
  int e0 = ei[e];
  int e1 = ei[N_EDGES + e];
  // each lane computes alpha for head = lane&7 (replicated 8x across wave)
  int hh = lane & 7;
  float m  = dec_f32(m_enc[(size_t)e0 * 8 + hh]);
  float lg = s_src[(size_t)e0 * 8 + hh] + s_dst[(size_t)e1 * 8 + hh];
  lg = lg >= 0.f ? lg : SLOPE * lg;
  float myAlpha = __expf(lg - m) / (denom[(size_t)e0 * 8 + hh] + EPS_F);
  const float* hp = h + (size_t)e1 * NHD;
  float* op = out + (size_t)e0 * NHD;
#pragma unroll
  for (int i = 0; i < 4; ++i) {
    int c = lane + 64 * i;                 // 0..255
    float alpha = __shfl(myAlpha, c >> 5, 64);
    atomAddF(&op[c], alpha * hp[c]);
  }
}

extern "C" void kernel_launch(void* const* d_in, const int* in_sizes, int n_in,
                              void* d_out, int out_size, void* d_ws, size_t ws_size,
                              hipStream_t stream) {
  const float* x  = (const float*)d_in[0];
  const int*   ei = (const int*)d_in[1];     // harness passes integers as int32
  const float* W  = (const float*)d_in[2];
  const float* a  = (const float*)d_in[3];
  float* out = (float*)d_out;

  // workspace layout (57.6 MB total)
  float* h      = (float*)d_ws;
  float* s_src  = h + (size_t)N_NODES * NHD;
  float* s_dst  = s_src + (size_t)N_NODES * HEADS;
  unsigned int* m_enc = (unsigned int*)(s_dst + (size_t)N_NODES * HEADS);
  float* denom  = (float*)(m_enc + (size_t)N_NODES * HEADS);

  hipMemsetAsync(d_out, 0, (size_t)N_NODES * NHD * sizeof(float), stream);
  // m_enc (encodes "-inf" as 0) and denom (0.0f) are contiguous -> one memset
  hipMemsetAsync(m_enc, 0, (size_t)N_NODES * HEADS * sizeof(unsigned int) * 2, stream);

  dim3 gg((N_NODES + BM - 1) / BM, NHD / BN);
  k_gemm<<<gg, 256, 0, stream>>>(x, W, h);
  k_scores<<<(N_NODES * HEADS + 255) / 256, 256, 0, stream>>>(h, a, s_src, s_dst);
  k_edge_max<<<(N_EDGES + 255) / 256, 256, 0, stream>>>(ei, s_src, s_dst, m_enc);
  k_edge_den<<<(N_EDGES + 255) / 256, 256, 0, stream>>>(ei, s_src, s_dst, m_enc, denom);
  k_scatter<<<(size_t)N_EDGES * 64 / 256, 256, 0, stream>>>(ei, h, s_src, s_dst, m_enc, denom, out);
}

// Round 3
// 380.547 us; speedup vs baseline: 4.0897x; 4.0897x over previous
//
#include <hip/hip_runtime.h>

#define N_NODES 50000
#define N_EDGES 800000
#define IN_F    512
#define HEADS   8
#define DHEAD   32
#define NHD     256            // HEADS*DHEAD
#define SLOPE   0.2f
#define EPS_F   1e-16f

typedef __attribute__((ext_vector_type(8))) short short8;
typedef __attribute__((ext_vector_type(4))) float f32x4;

__device__ __forceinline__ unsigned short f2bf(float f) {
  unsigned int u = __float_as_uint(f);
  unsigned int r = u + 0x7FFFu + ((u >> 16) & 1u);   // round-to-nearest-even
  return (unsigned short)(r >> 16);
}

// ---- cast W[h][k][d] (f32) -> WbT[c][k] (bf16), c = h*32+d
__global__ void k_cast_w(const float* __restrict__ W, unsigned short* __restrict__ WbT) {
  int id = blockIdx.x * blockDim.x + threadIdx.x;
  if (id >= NHD * IN_F) return;
  int c = id >> 9, k = id & 511;
  WbT[id] = f2bf(W[(c >> 5) * (IN_F * DHEAD) + k * DHEAD + (c & 31)]);
}

// ---- MFMA GEMM: h[m][c] = sum_k x[m][k] * WbT[c][k], tile 128x256, 8 waves
// LDS layout: As[m][32] / Bs[n][32] bf16, 16B k-quads XOR-swizzled by ((row>>1)&3)
// so 16 lanes of a ds_read_b128 hit 8 distinct bank-quads (2-way = free).
__global__ __launch_bounds__(512) void k_gemm_mfma(const float* __restrict__ x,
                                                   const unsigned short* __restrict__ WbT,
                                                   float* __restrict__ h) {
  __shared__ unsigned short As[128 * 32];
  __shared__ unsigned short Bs[256 * 32];
  const int tid  = threadIdx.x;
  const int bm   = blockIdx.x * 128;
  const int wid  = tid >> 6;
  const int lane = tid & 63;
  const int wm   = (wid >> 2) * 64;    // 0 / 64
  const int wn   = (wid & 3) * 64;     // 0 / 64 / 128 / 192

  // A staging: 512 slots (128 rows x 4 k-quads), one per thread
  const int am    = tid >> 2;
  const int aslot = tid & 3;
  const int akq   = aslot ^ ((am >> 1) & 3);
  const int arow  = min(bm + am, N_NODES - 1);
  const float* aptr = x + (size_t)arow * IN_F + akq * 8;
  unsigned short* awr = &As[am * 32 + aslot * 8];

  // B staging: 1024 slots, two per thread (n and n+128; swizzle identical)
  const int bn    = tid >> 2;
  const int bslot = tid & 3;
  const int bkq   = bslot ^ ((bn >> 1) & 3);
  const unsigned short* bptr0 = WbT + (size_t)bn * IN_F + bkq * 8;
  const unsigned short* bptr1 = WbT + (size_t)(bn + 128) * IN_F + bkq * 8;
  unsigned short* bwr0 = &Bs[bn * 32 + bslot * 8];
  unsigned short* bwr1 = &Bs[(bn + 128) * 32 + bslot * 8];

  f32x4 acc[4][4] = {};

  for (int k0 = 0; k0 < IN_F; k0 += 32) {
    __syncthreads();
    float4 a0 = *(const float4*)(aptr + k0);
    float4 a1 = *(const float4*)(aptr + k0 + 4);
    short8 bv0 = *(const short8*)(bptr0 + k0);
    short8 bv1 = *(const short8*)(bptr1 + k0);
    short8 av;
    av[0] = (short)f2bf(a0.x); av[1] = (short)f2bf(a0.y);
    av[2] = (short)f2bf(a0.z); av[3] = (short)f2bf(a0.w);
    av[4] = (short)f2bf(a1.x); av[5] = (short)f2bf(a1.y);
    av[6] = (short)f2bf(a1.z); av[7] = (short)f2bf(a1.w);
    *(short8*)awr  = av;
    *(short8*)bwr0 = bv0;
    *(short8*)bwr1 = bv1;
    __syncthreads();

    short8 af[4], bfr[4];
#pragma unroll
    for (int i = 0; i < 4; ++i) {
      int r = wm + i * 16 + (lane & 15);
      int slot = (lane >> 4) ^ ((r >> 1) & 3);
      af[i] = *(const short8*)&As[r * 32 + slot * 8];
    }
#pragma unroll
    for (int j = 0; j < 4; ++j) {
      int r = wn + j * 16 + (lane & 15);
      int slot = (lane >> 4) ^ ((r >> 1) & 3);
      bfr[j] = *(const short8*)&Bs[r * 32 + slot * 8];
    }
#pragma unroll
    for (int i = 0; i < 4; ++i)
#pragma unroll
      for (int j = 0; j < 4; ++j)
        acc[i][j] = __builtin_amdgcn_mfma_f32_16x16x32_bf16(af[i], bfr[j], acc[i][j], 0, 0, 0);
  }

  // epilogue: C/D layout col=lane&15, row=(lane>>4)*4+q
#pragma unroll
  for (int i = 0; i < 4; ++i) {
#pragma unroll
    for (int q = 0; q < 4; ++q) {
      int row = bm + wm + i * 16 + (lane >> 4) * 4 + q;
      if (row < N_NODES) {
#pragma unroll
        for (int j = 0; j < 4; ++j) {
          int col = wn + j * 16 + (lane & 15);
          h[(size_t)row * NHD + col] = acc[i][j][q];
        }
      }
    }
  }
}

// ---- scores: one wave per node, 8-lane-group reduce
__global__ __launch_bounds__(256) void k_scores(const float* __restrict__ h,
                                                const float* __restrict__ a,
                                                float* __restrict__ s_src,
                                                float* __restrict__ s_dst) {
  int n = (blockIdx.x * blockDim.x + threadIdx.x) >> 6;
  int lane = threadIdx.x & 63;
  if (n >= N_NODES) return;
  int head = lane >> 3;
  int dofs = (lane & 7) * 4;
  const float4 hv = *(const float4*)(h + (size_t)n * NHD + lane * 4);
  const float4 as = *(const float4*)(a + head * 2 * DHEAD + dofs);
  const float4 ad = *(const float4*)(a + head * 2 * DHEAD + DHEAD + dofs);
  float ss = hv.x * as.x + hv.y * as.y + hv.z * as.z + hv.w * as.w;
  float sd = hv.x * ad.x + hv.y * ad.y + hv.z * ad.z + hv.w * ad.w;
  ss += __shfl_xor(ss, 1); ss += __shfl_xor(ss, 2); ss += __shfl_xor(ss, 4);
  sd += __shfl_xor(sd, 1); sd += __shfl_xor(sd, 2); sd += __shfl_xor(sd, 4);
  if ((lane & 7) == 0) {
    s_src[n * 8 + head] = ss;
    s_dst[n * 8 + head] = sd;
  }
}

// ---- CSR build
__global__ void k_hist(const int* __restrict__ ei, int* __restrict__ deg) {
  int e = blockIdx.x * blockDim.x + threadIdx.x;
  if (e < N_EDGES) atomicAdd(&deg[ei[e]], 1);
}

__global__ __launch_bounds__(1024) void k_scan(const int* __restrict__ deg,
                                               int* __restrict__ rowptr,
                                               int* __restrict__ cursor) {
  __shared__ int sm[1024];
  const int t = threadIdx.x;
  const int CH = 49;                      // 1024*49 >= 50000
  int b = t * CH;
  int e = min(b + CH, N_NODES);
  int s = 0;
  for (int i = b; i < e; ++i) s += deg[i];
  sm[t] = s;
  __syncthreads();
  for (int off = 1; off < 1024; off <<= 1) {
    int v = (t >= off) ? sm[t - off] : 0;
    __syncthreads();
    sm[t] += v;
    __syncthreads();
  }
  int run = sm[t] - s;                    // exclusive prefix
  for (int i = b; i < e; ++i) { rowptr[i] = run; cursor[i] = run; run += deg[i]; }
  if (t == 1023) rowptr[N_NODES] = sm[1023];
}

__global__ void k_fill(const int* __restrict__ ei, int* __restrict__ cursor,
                       int* __restrict__ edst) {
  int e = blockIdx.x * blockDim.x + threadIdx.x;
  if (e >= N_EDGES) return;
  int p = atomicAdd(&cursor[ei[e]], 1);
  edst[p] = ei[N_EDGES + e];
}

// ---- fused per-node online-softmax aggregation: one wave per node, no atomics
__global__ __launch_bounds__(256) void k_aggr(const int* __restrict__ rowptr,
                                              const int* __restrict__ edst,
                                              const float* __restrict__ s_src,
                                              const float* __restrict__ s_dst,
                                              const float* __restrict__ h,
                                              float* __restrict__ out) {
  int n = (blockIdx.x * blockDim.x + threadIdx.x) >> 6;
  int lane = threadIdx.x & 63;
  if (n >= N_NODES) return;
  int head = lane >> 3;                      // 8 lanes per head, 4 channels each
  float ssrc = s_src[n * 8 + head];
  int i = rowptr[n], iend = rowptr[n + 1];
  float m = -1e30f, den = 0.f;
  f32x4 acc = {0.f, 0.f, 0.f, 0.f};
  for (; i < iend; ++i) {
    int dst = edst[i];
    float v = ssrc + s_dst[dst * 8 + head];
    v = v >= 0.f ? v : SLOPE * v;
    float mn = fmaxf(m, v);
    float scale = __expf(m - mn);            // first iter: exp(-1e30) = 0
    float ex = __expf(v - mn);
    f32x4 hv = *(const f32x4*)(h + (size_t)dst * NHD + lane * 4);
    den = den * scale + ex;
    acc = acc * scale + ex * hv;
    m = mn;
  }
  float inv = 1.f / (den + EPS_F);           // deg==0: acc=0 -> out=0
  *(f32x4*)(out + (size_t)n * NHD + lane * 4) = acc * inv;
}

extern "C" void kernel_launch(void* const* d_in, const int* in_sizes, int n_in,
                              void* d_out, int out_size, void* d_ws, size_t ws_size,
                              hipStream_t stream) {
  const float* x  = (const float*)d_in[0];
  const int*   ei = (const int*)d_in[1];
  const float* W  = (const float*)d_in[2];
  const float* a  = (const float*)d_in[3];
  float* out = (float*)d_out;

  // workspace layout (~58.5 MB, all 16B-aligned)
  float* h = (float*)d_ws;                                   // 12,800,000 f
  float* s_src = h + (size_t)N_NODES * NHD;                  // 400,000 f
  float* s_dst = s_src + (size_t)N_NODES * HEADS;            // 400,000 f
  unsigned short* WbT = (unsigned short*)(s_dst + (size_t)N_NODES * HEADS); // 131,072 u16
  int* deg    = (int*)(WbT + (size_t)NHD * IN_F);            // 50,000
  int* cursor = deg + N_NODES;                               // 50,000
  int* rowptr = cursor + N_NODES;                            // 50,001 (pad to 50,008)
  int* edst   = rowptr + 50008;                              // 800,000

  hipMemsetAsync(deg, 0, (size_t)N_NODES * sizeof(int), stream);
  k_cast_w<<<(NHD * IN_F + 255) / 256, 256, 0, stream>>>(W, WbT);
  k_gemm_mfma<<<(N_NODES + 127) / 128, 512, 0, stream>>>(x, WbT, h);
  k_scores<<<(N_NODES * 64 + 255) / 256, 256, 0, stream>>>(h, a, s_src, s_dst);
  k_hist<<<(N_EDGES + 255) / 256, 256, 0, stream>>>(ei, deg);
  k_scan<<<1, 1024, 0, stream>>>(deg, rowptr, cursor);
  k_fill<<<(N_EDGES + 255) / 256, 256, 0, stream>>>(ei, cursor, edst);
  k_aggr<<<(N_NODES * 64 + 255) / 256, 256, 0, stream>>>(rowptr, edst, s_src, s_dst, h, out);
}

// Round 4
// 307.124 us; speedup vs baseline: 5.0674x; 1.2391x over previous
//
#include <hip/hip_runtime.h>

#define N_NODES 50000
#define N_EDGES 800000
#define IN_F    512
#define HEADS   8
#define DHEAD   32
#define NHD     256            // HEADS*DHEAD
#define SLOPE   0.2f
#define EPS_F   1e-16f

typedef __attribute__((ext_vector_type(8))) short short8;
typedef __attribute__((ext_vector_type(4))) float f32x4;
typedef __attribute__((ext_vector_type(4))) unsigned short u16x4;

__device__ __forceinline__ unsigned short f2bf(float f) {
  unsigned int u = __float_as_uint(f);
  unsigned int r = u + 0x7FFFu + ((u >> 16) & 1u);   // round-to-nearest-even
  return (unsigned short)(r >> 16);
}
__device__ __forceinline__ float bf2f(unsigned short s) {
  return __uint_as_float(((unsigned int)s) << 16);
}
__device__ __forceinline__ void gload_lds16(const void* g, void* l) {
  __builtin_amdgcn_global_load_lds((const __attribute__((address_space(1))) void*)g,
                                   (__attribute__((address_space(3))) void*)l, 16, 0, 0);
}

// ---- cast W[h][k][d] (f32) -> WbT[c][k] (bf16), c = h*32+d
__global__ void k_cast_w(const float* __restrict__ W, unsigned short* __restrict__ WbT) {
  int id = blockIdx.x * blockDim.x + threadIdx.x;
  if (id >= NHD * IN_F) return;
  int c = id >> 9, k = id & 511;
  WbT[id] = f2bf(W[(c >> 5) * (IN_F * DHEAD) + k * DHEAD + (c & 31)]);
}

// ---- MFMA GEMM: hb[m][c] (bf16) = sum_k x[m][k] * WbT[c][k]
// tile 64(M)x256(N), BK=64, 256 threads = 4 waves (each wave 64x64).
// LDS: 16B k-quads, quad position p = q ^ (row&7) -> ds_read_b128 2-way = free.
// B staged async via global_load_lds (pre-swizzled global source, linear LDS).
__global__ __launch_bounds__(256) void k_gemm_mfma(const float* __restrict__ x,
                                                   const unsigned short* __restrict__ WbT,
                                                   unsigned short* __restrict__ hb) {
  __shared__ unsigned short As[64 * 64];    // 8 KB
  __shared__ unsigned short Bs[256 * 64];   // 32 KB
  const int tid  = threadIdx.x;
  const int lane = tid & 63;
  const int wid  = tid >> 6;
  const int bm   = blockIdx.x * 64;
  const int wn   = wid * 64;

  // A staging (reg + f32->bf16 cast): slots s = tid and tid+256
  const int arow = tid >> 3, ap = tid & 7, aq = ap ^ (arow & 7);
  const float* gA0 = x + (size_t)min(bm + arow,      N_NODES - 1) * IN_F + aq * 8;
  const float* gA1 = x + (size_t)min(bm + arow + 32, N_NODES - 1) * IN_F + aq * 8;
  unsigned short* lA0 = &As[(arow * 8 + ap) * 8];
  unsigned short* lA1 = &As[((arow + 32) * 8 + ap) * 8];

  // B staging (async): wave wid stages slots 512*wid + 64*it + lane, it=0..7
  const int bs = 512 * wid + lane;
  const int brow = bs >> 3, bp = bs & 7, bq = bp ^ (brow & 7);
  const unsigned short* gB = WbT + (size_t)brow * IN_F + bq * 8;
  unsigned short* lB = &Bs[(size_t)512 * wid * 8];

  f32x4 acc[4][4] = {};

  for (int k0 = 0; k0 < IN_F; k0 += 64) {
    __syncthreads();
#pragma unroll
    for (int it = 0; it < 8; ++it)
      gload_lds16(gB + k0 + it * 8 * IN_F, lB + it * 64 * 8);
    {
      float4 a00 = *(const float4*)(gA0 + k0);
      float4 a01 = *(const float4*)(gA0 + k0 + 4);
      float4 a10 = *(const float4*)(gA1 + k0);
      float4 a11 = *(const float4*)(gA1 + k0 + 4);
      short8 v0, v1;
      v0[0] = (short)f2bf(a00.x); v0[1] = (short)f2bf(a00.y);
      v0[2] = (short)f2bf(a00.z); v0[3] = (short)f2bf(a00.w);
      v0[4] = (short)f2bf(a01.x); v0[5] = (short)f2bf(a01.y);
      v0[6] = (short)f2bf(a01.z); v0[7] = (short)f2bf(a01.w);
      v1[0] = (short)f2bf(a10.x); v1[1] = (short)f2bf(a10.y);
      v1[2] = (short)f2bf(a10.z); v1[3] = (short)f2bf(a10.w);
      v1[4] = (short)f2bf(a11.x); v1[5] = (short)f2bf(a11.y);
      v1[6] = (short)f2bf(a11.z); v1[7] = (short)f2bf(a11.w);
      *(short8*)lA0 = v0;
      *(short8*)lA1 = v1;
    }
    __syncthreads();

#pragma unroll
    for (int kk = 0; kk < 2; ++kk) {
      short8 af[4], bfr[4];
#pragma unroll
      for (int i = 0; i < 4; ++i) {
        int r = i * 16 + (lane & 15);
        int q = kk * 4 + (lane >> 4);
        af[i] = *(const short8*)&As[(r * 8 + (q ^ (r & 7))) * 8];
      }
#pragma unroll
      for (int j = 0; j < 4; ++j) {
        int r = wn + j * 16 + (lane & 15);
        int q = kk * 4 + (lane >> 4);
        bfr[j] = *(const short8*)&Bs[(r * 8 + (q ^ (r & 7))) * 8];
      }
#pragma unroll
      for (int i = 0; i < 4; ++i)
#pragma unroll
        for (int j = 0; j < 4; ++j)
          acc[i][j] = __builtin_amdgcn_mfma_f32_16x16x32_bf16(af[i], bfr[j], acc[i][j], 0, 0, 0);
    }
  }

  // epilogue: C/D layout col=lane&15, row=(lane>>4)*4+q ; write bf16 h
#pragma unroll
  for (int i = 0; i < 4; ++i) {
#pragma unroll
    for (int q = 0; q < 4; ++q) {
      int row = bm + i * 16 + (lane >> 4) * 4 + q;
      if (row < N_NODES) {
#pragma unroll
        for (int j = 0; j < 4; ++j)
          hb[(size_t)row * NHD + wn + j * 16 + (lane & 15)] = f2bf(acc[i][j][q]);
      }
    }
  }
}

// ---- scores: one wave per node, 8-lane-group reduce (bf16 h)
__global__ __launch_bounds__(256) void k_scores(const unsigned short* __restrict__ hb,
                                                const float* __restrict__ a,
                                                float* __restrict__ s_src,
                                                float* __restrict__ s_dst) {
  int n = (blockIdx.x * blockDim.x + threadIdx.x) >> 6;
  int lane = threadIdx.x & 63;
  if (n >= N_NODES) return;
  int head = lane >> 3;
  int dofs = (lane & 7) * 4;
  u16x4 hv = *(const u16x4*)(hb + (size_t)n * NHD + lane * 4);
  float4 as = *(const float4*)(a + head * 2 * DHEAD + dofs);
  float4 ad = *(const float4*)(a + head * 2 * DHEAD + DHEAD + dofs);
  float h0 = bf2f(hv.x), h1 = bf2f(hv.y), h2 = bf2f(hv.z), h3 = bf2f(hv.w);
  float ss = h0 * as.x + h1 * as.y + h2 * as.z + h3 * as.w;
  float sd = h0 * ad.x + h1 * ad.y + h2 * ad.z + h3 * ad.w;
  ss += __shfl_xor(ss, 1); ss += __shfl_xor(ss, 2); ss += __shfl_xor(ss, 4);
  sd += __shfl_xor(sd, 1); sd += __shfl_xor(sd, 2); sd += __shfl_xor(sd, 4);
  if ((lane & 7) == 0) {
    s_src[n * 8 + head] = ss;
    s_dst[n * 8 + head] = sd;
  }
}

// ---- CSR build
__global__ void k_hist(const int* __restrict__ ei, int* __restrict__ deg) {
  int e = blockIdx.x * blockDim.x + threadIdx.x;
  if (e < N_EDGES) atomicAdd(&deg[ei[e]], 1);
}

__global__ __launch_bounds__(1024) void k_scan(const int* __restrict__ deg,
                                               int* __restrict__ rowptr,
                                               int* __restrict__ cursor) {
  __shared__ int sm[1024];
  const int t = threadIdx.x;
  const int CH = 49;                      // 1024*49 >= 50000
  int b = t * CH;
  int e = min(b + CH, N_NODES);
  int s = 0;
  for (int i = b; i < e; ++i) s += deg[i];
  sm[t] = s;
  __syncthreads();
  for (int off = 1; off < 1024; off <<= 1) {
    int v = (t >= off) ? sm[t - off] : 0;
    __syncthreads();
    sm[t] += v;
    __syncthreads();
  }
  int run = sm[t] - s;                    // exclusive prefix
  for (int i = b; i < e; ++i) { rowptr[i] = run; cursor[i] = run; run += deg[i]; }
  if (t == 1023) rowptr[N_NODES] = sm[1023];
}

__global__ void k_fill(const int* __restrict__ ei, int* __restrict__ cursor,
                       int* __restrict__ edst) {
  int e = blockIdx.x * blockDim.x + threadIdx.x;
  if (e >= N_EDGES) return;
  int p = atomicAdd(&cursor[ei[e]], 1);
  edst[p] = ei[N_EDGES + e];
}

// ---- fused aggregation: one wave per node; softmax shift-invariance (m=0),
// no serial rescale chain, 2-way unrolled, bf16 h gather (8B/lane/edge)
__global__ __launch_bounds__(256) void k_aggr(const int* __restrict__ rowptr,
                                              const int* __restrict__ edst,
                                              const float* __restrict__ s_src,
                                              const float* __restrict__ s_dst,
                                              const unsigned short* __restrict__ hb,
                                              float* __restrict__ out) {
  int n = (int)((blockIdx.x * blockDim.x + threadIdx.x) >> 6);
  if (n >= N_NODES) return;
  n = __builtin_amdgcn_readfirstlane(n);
  const int lane = threadIdx.x & 63;
  const int head = lane >> 3;
  const float ssrc = s_src[n * 8 + head];
  int i = rowptr[n];
  const int iend = rowptr[n + 1];
  float den = 0.f;
  f32x4 acc = {0.f, 0.f, 0.f, 0.f};
  for (; i + 1 < iend; i += 2) {
    int d0 = edst[i], d1 = edst[i + 1];
    float v0 = ssrc + s_dst[d0 * 8 + head];
    float v1 = ssrc + s_dst[d1 * 8 + head];
    u16x4 h0 = *(const u16x4*)(hb + (size_t)d0 * NHD + lane * 4);
    u16x4 h1 = *(const u16x4*)(hb + (size_t)d1 * NHD + lane * 4);
    v0 = v0 >= 0.f ? v0 : SLOPE * v0;
    v1 = v1 >= 0.f ? v1 : SLOPE * v1;
    float e0 = __expf(v0), e1 = __expf(v1);
    den += e0 + e1;
    acc.x += e0 * bf2f(h0.x) + e1 * bf2f(h1.x);
    acc.y += e0 * bf2f(h0.y) + e1 * bf2f(h1.y);
    acc.z += e0 * bf2f(h0.z) + e1 * bf2f(h1.z);
    acc.w += e0 * bf2f(h0.w) + e1 * bf2f(h1.w);
  }
  if (i < iend) {
    int d0 = edst[i];
    float v0 = ssrc + s_dst[d0 * 8 + head];
    v0 = v0 >= 0.f ? v0 : SLOPE * v0;
    float e0 = __expf(v0);
    u16x4 h0 = *(const u16x4*)(hb + (size_t)d0 * NHD + lane * 4);
    den += e0;
    acc.x += e0 * bf2f(h0.x);
    acc.y += e0 * bf2f(h0.y);
    acc.z += e0 * bf2f(h0.z);
    acc.w += e0 * bf2f(h0.w);
  }
  float inv = 1.f / (den + EPS_F);         // deg==0: acc=0 -> out=0
  *(f32x4*)(out + (size_t)n * NHD + lane * 4) = acc * inv;
}

extern "C" void kernel_launch(void* const* d_in, const int* in_sizes, int n_in,
                              void* d_out, int out_size, void* d_ws, size_t ws_size,
                              hipStream_t stream) {
  const float* x  = (const float*)d_in[0];
  const int*   ei = (const int*)d_in[1];
  const float* W  = (const float*)d_in[2];
  const float* a  = (const float*)d_in[3];
  float* out = (float*)d_out;

  // workspace layout (~33 MB, 16B-aligned blocks)
  unsigned short* hb  = (unsigned short*)d_ws;                 // 12,800,000 u16
  unsigned short* WbT = hb + (size_t)N_NODES * NHD;            // 131,072 u16
  float* s_src = (float*)(WbT + (size_t)NHD * IN_F);           // 400,000 f
  float* s_dst = s_src + (size_t)N_NODES * HEADS;              // 400,000 f
  int* deg    = (int*)(s_dst + (size_t)N_NODES * HEADS);       // 50,000
  int* cursor = deg + N_NODES;                                 // 50,000
  int* rowptr = cursor + N_NODES;                              // 50,001 (pad 50,008)
  int* edst   = rowptr + 50008;                                // 800,000

  hipMemsetAsync(deg, 0, (size_t)N_NODES * sizeof(int), stream);
  k_cast_w<<<(NHD * IN_F + 255) / 256, 256, 0, stream>>>(W, WbT);
  k_gemm_mfma<<<(N_NODES + 63) / 64, 256, 0, stream>>>(x, WbT, hb);
  k_scores<<<(N_NODES * 64 + 255) / 256, 256, 0, stream>>>(hb, a, s_src, s_dst);
  k_hist<<<(N_EDGES + 255) / 256, 256, 0, stream>>>(ei, deg);
  k_scan<<<1, 1024, 0, stream>>>(deg, rowptr, cursor);
  k_fill<<<(N_EDGES + 255) / 256, 256, 0, stream>>>(ei, cursor, edst);
  k_aggr<<<(N_NODES * 64 + 255) / 256, 256, 0, stream>>>(rowptr, edst, s_src, s_dst, hb, out);
}

// Round 5
// 204.192 us; speedup vs baseline: 7.6218x; 1.5041x over previous
//
#include <hip/hip_runtime.h>

#define N_NODES 50000
#define N_EDGES 800000
#define IN_F    512
#define HEADS   8
#define DHEAD   32
#define NHD     256            // HEADS*DHEAD
#define SLOPE   0.2f
#define EPS_F   1e-16f
#define N_SBLK  ((N_NODES + 255) / 256)   // 196 scan blocks

typedef __attribute__((ext_vector_type(8))) short short8;
typedef __attribute__((ext_vector_type(4))) float f32x4;
typedef __attribute__((ext_vector_type(4))) unsigned short u16x4;

__device__ __forceinline__ unsigned short f2bf(float f) {
  unsigned int u = __float_as_uint(f);
  unsigned int r = u + 0x7FFFu + ((u >> 16) & 1u);   // round-to-nearest-even
  return (unsigned short)(r >> 16);
}
__device__ __forceinline__ float bf2f(unsigned short s) {
  return __uint_as_float(((unsigned int)s) << 16);
}
__device__ __forceinline__ void gload_lds16(const void* g, void* l) {
  __builtin_amdgcn_global_load_lds((const __attribute__((address_space(1))) void*)g,
                                   (__attribute__((address_space(3))) void*)l, 16, 0, 0);
}

// ---- cast W[h][k][d] (f32) -> WbT[c][k] (bf16), c = h*32+d
__global__ void k_cast_w(const float* __restrict__ W, unsigned short* __restrict__ WbT) {
  int id = blockIdx.x * blockDim.x + threadIdx.x;
  if (id >= NHD * IN_F) return;
  int c = id >> 9, k = id & 511;
  WbT[id] = f2bf(W[(c >> 5) * (IN_F * DHEAD) + k * DHEAD + (c & 31)]);
}

// ---- MFMA GEMM: hb[m][c] (bf16) = sum_k x[m][k] * WbT[c][k]
// tile 64(M)x256(N), BK=64, 256 threads = 4 waves (each wave 64x64).
// LDS: 16B k-quads, quad position p = q ^ (row&7) -> ds_read_b128 2-way = free.
// B staged async via global_load_lds (pre-swizzled global source, linear LDS).
__global__ __launch_bounds__(256) void k_gemm_mfma(const float* __restrict__ x,
                                                   const unsigned short* __restrict__ WbT,
                                                   unsigned short* __restrict__ hb) {
  __shared__ unsigned short As[64 * 64];    // 8 KB
  __shared__ unsigned short Bs[256 * 64];   // 32 KB
  const int tid  = threadIdx.x;
  const int lane = tid & 63;
  const int wid  = tid >> 6;
  const int bm   = blockIdx.x * 64;
  const int wn   = wid * 64;

  // A staging (reg + f32->bf16 cast): slots s = tid and tid+256
  const int arow = tid >> 3, ap = tid & 7, aq = ap ^ (arow & 7);
  const float* gA0 = x + (size_t)min(bm + arow,      N_NODES - 1) * IN_F + aq * 8;
  const float* gA1 = x + (size_t)min(bm + arow + 32, N_NODES - 1) * IN_F + aq * 8;
  unsigned short* lA0 = &As[(arow * 8 + ap) * 8];
  unsigned short* lA1 = &As[((arow + 32) * 8 + ap) * 8];

  // B staging (async): wave wid stages slots 512*wid + 64*it + lane, it=0..7
  const int bs = 512 * wid + lane;
  const int brow = bs >> 3, bp = bs & 7, bq = bp ^ (brow & 7);
  const unsigned short* gB = WbT + (size_t)brow * IN_F + bq * 8;
  unsigned short* lB = &Bs[(size_t)512 * wid * 8];

  f32x4 acc[4][4] = {};

  for (int k0 = 0; k0 < IN_F; k0 += 64) {
    __syncthreads();
#pragma unroll
    for (int it = 0; it < 8; ++it)
      gload_lds16(gB + k0 + it * 8 * IN_F, lB + it * 64 * 8);
    {
      float4 a00 = *(const float4*)(gA0 + k0);
      float4 a01 = *(const float4*)(gA0 + k0 + 4);
      float4 a10 = *(const float4*)(gA1 + k0);
      float4 a11 = *(const float4*)(gA1 + k0 + 4);
      short8 v0, v1;
      v0[0] = (short)f2bf(a00.x); v0[1] = (short)f2bf(a00.y);
      v0[2] = (short)f2bf(a00.z); v0[3] = (short)f2bf(a00.w);
      v0[4] = (short)f2bf(a01.x); v0[5] = (short)f2bf(a01.y);
      v0[6] = (short)f2bf(a01.z); v0[7] = (short)f2bf(a01.w);
      v1[0] = (short)f2bf(a10.x); v1[1] = (short)f2bf(a10.y);
      v1[2] = (short)f2bf(a10.z); v1[3] = (short)f2bf(a10.w);
      v1[4] = (short)f2bf(a11.x); v1[5] = (short)f2bf(a11.y);
      v1[6] = (short)f2bf(a11.z); v1[7] = (short)f2bf(a11.w);
      *(short8*)lA0 = v0;
      *(short8*)lA1 = v1;
    }
    __syncthreads();

#pragma unroll
    for (int kk = 0; kk < 2; ++kk) {
      short8 af[4], bfr[4];
#pragma unroll
      for (int i = 0; i < 4; ++i) {
        int r = i * 16 + (lane & 15);
        int q = kk * 4 + (lane >> 4);
        af[i] = *(const short8*)&As[(r * 8 + (q ^ (r & 7))) * 8];
      }
#pragma unroll
      for (int j = 0; j < 4; ++j) {
        int r = wn + j * 16 + (lane & 15);
        int q = kk * 4 + (lane >> 4);
        bfr[j] = *(const short8*)&Bs[(r * 8 + (q ^ (r & 7))) * 8];
      }
#pragma unroll
      for (int i = 0; i < 4; ++i)
#pragma unroll
        for (int j = 0; j < 4; ++j)
          acc[i][j] = __builtin_amdgcn_mfma_f32_16x16x32_bf16(af[i], bfr[j], acc[i][j], 0, 0, 0);
    }
  }

  // epilogue: C/D layout col=lane&15, row=(lane>>4)*4+q ; write bf16 h
#pragma unroll
  for (int i = 0; i < 4; ++i) {
#pragma unroll
    for (int q = 0; q < 4; ++q) {
      int row = bm + i * 16 + (lane >> 4) * 4 + q;
      if (row < N_NODES) {
#pragma unroll
        for (int j = 0; j < 4; ++j)
          hb[(size_t)row * NHD + wn + j * 16 + (lane & 15)] = f2bf(acc[i][j][q]);
      }
    }
  }
}

// ---- scores: one wave per node, 8-lane-group reduce (bf16 h)
__global__ __launch_bounds__(256) void k_scores(const unsigned short* __restrict__ hb,
                                                const float* __restrict__ a,
                                                float* __restrict__ s_src,
                                                float* __restrict__ s_dst) {
  int n = (blockIdx.x * blockDim.x + threadIdx.x) >> 6;
  int lane = threadIdx.x & 63;
  if (n >= N_NODES) return;
  int head = lane >> 3;
  int dofs = (lane & 7) * 4;
  u16x4 hv = *(const u16x4*)(hb + (size_t)n * NHD + lane * 4);
  float4 as = *(const float4*)(a + head * 2 * DHEAD + dofs);
  float4 ad = *(const float4*)(a + head * 2 * DHEAD + DHEAD + dofs);
  float h0 = bf2f(hv.x), h1 = bf2f(hv.y), h2 = bf2f(hv.z), h3 = bf2f(hv.w);
  float ss = h0 * as.x + h1 * as.y + h2 * as.z + h3 * as.w;
  float sd = h0 * ad.x + h1 * ad.y + h2 * ad.z + h3 * ad.w;
  ss += __shfl_xor(ss, 1); ss += __shfl_xor(ss, 2); ss += __shfl_xor(ss, 4);
  sd += __shfl_xor(sd, 1); sd += __shfl_xor(sd, 2); sd += __shfl_xor(sd, 4);
  if ((lane & 7) == 0) {
    s_src[n * 8 + head] = ss;
    s_dst[n * 8 + head] = sd;
  }
}

// ---- CSR build
__global__ void k_hist(const int* __restrict__ ei, int* __restrict__ deg) {
  int e = blockIdx.x * blockDim.x + threadIdx.x;
  if (e < N_EDGES) atomicAdd(&deg[ei[e]], 1);
}

// per-block degree sums (196 blocks x 256)
__global__ __launch_bounds__(256) void k_bsum(const int* __restrict__ deg,
                                              int* __restrict__ bsum) {
  __shared__ int sm[4];
  int i = blockIdx.x * 256 + threadIdx.x;
  int v = (i < N_NODES) ? deg[i] : 0;
#pragma unroll
  for (int o = 1; o < 64; o <<= 1) v += __shfl_xor(v, o);
  if ((threadIdx.x & 63) == 0) sm[threadIdx.x >> 6] = v;
  __syncthreads();
  if (threadIdx.x == 0) bsum[blockIdx.x] = sm[0] + sm[1] + sm[2] + sm[3];
}

// full scan: each block re-scans the 196 block sums (cheap), then scans its
// own 256 degrees, writes rowptr/cursor; block0 writes rowptr[N]
__global__ __launch_bounds__(256) void k_scan_main(const int* __restrict__ deg,
                                                   const int* __restrict__ bsum,
                                                   int* __restrict__ rowptr,
                                                   int* __restrict__ cursor) {
  __shared__ int sb[256];
  __shared__ int sm[256];
  const int t = threadIdx.x;
  const int b = blockIdx.x;
  int bv = (t < N_SBLK) ? bsum[t] : 0;
  sb[t] = bv;
  int i = b * 256 + t;
  int v = (i < N_NODES) ? deg[i] : 0;
  sm[t] = v;
  __syncthreads();
#pragma unroll
  for (int o = 1; o < 256; o <<= 1) {
    int u1 = (t >= o) ? sb[t - o] : 0;
    int u2 = (t >= o) ? sm[t - o] : 0;
    __syncthreads();
    sb[t] += u1;
    sm[t] += u2;
    __syncthreads();
  }
  int boff = (b > 0) ? sb[b - 1] : 0;
  if (i < N_NODES) {
    int ex = boff + sm[t] - v;
    rowptr[i] = ex;
    cursor[i] = ex;
  }
  if (b == 0 && t == 0) rowptr[N_NODES] = sb[255];   // total
}

__global__ void k_fill(const int* __restrict__ ei, int* __restrict__ cursor,
                       int* __restrict__ edst) {
  int e = blockIdx.x * blockDim.x + threadIdx.x;
  if (e >= N_EDGES) return;
  int p = atomicAdd(&cursor[ei[e]], 1);
  edst[p] = ei[N_EDGES + e];
}

// ---- fused aggregation: one wave per node; softmax shift-invariance (m=0),
// no serial rescale chain, 2-way unrolled, bf16 h gather (8B/lane/edge)
__global__ __launch_bounds__(256) void k_aggr(const int* __restrict__ rowptr,
                                              const int* __restrict__ edst,
                                              const float* __restrict__ s_src,
                                              const float* __restrict__ s_dst,
                                              const unsigned short* __restrict__ hb,
                                              float* __restrict__ out) {
  int n = (int)((blockIdx.x * blockDim.x + threadIdx.x) >> 6);
  if (n >= N_NODES) return;
  n = __builtin_amdgcn_readfirstlane(n);
  const int lane = threadIdx.x & 63;
  const int head = lane >> 3;
  const float ssrc = s_src[n * 8 + head];
  int i = rowptr[n];
  const int iend = rowptr[n + 1];
  float den = 0.f;
  f32x4 acc = {0.f, 0.f, 0.f, 0.f};
  for (; i + 1 < iend; i += 2) {
    int d0 = edst[i], d1 = edst[i + 1];
    float v0 = ssrc + s_dst[d0 * 8 + head];
    float v1 = ssrc + s_dst[d1 * 8 + head];
    u16x4 h0 = *(const u16x4*)(hb + (size_t)d0 * NHD + lane * 4);
    u16x4 h1 = *(const u16x4*)(hb + (size_t)d1 * NHD + lane * 4);
    v0 = v0 >= 0.f ? v0 : SLOPE * v0;
    v1 = v1 >= 0.f ? v1 : SLOPE * v1;
    float e0 = __expf(v0), e1 = __expf(v1);
    den += e0 + e1;
    acc.x += e0 * bf2f(h0.x) + e1 * bf2f(h1.x);
    acc.y += e0 * bf2f(h0.y) + e1 * bf2f(h1.y);
    acc.z += e0 * bf2f(h0.z) + e1 * bf2f(h1.z);
    acc.w += e0 * bf2f(h0.w) + e1 * bf2f(h1.w);
  }
  if (i < iend) {
    int d0 = edst[i];
    float v0 = ssrc + s_dst[d0 * 8 + head];
    v0 = v0 >= 0.f ? v0 : SLOPE * v0;
    float e0 = __expf(v0);
    u16x4 h0 = *(const u16x4*)(hb + (size_t)d0 * NHD + lane * 4);
    den += e0;
    acc.x += e0 * bf2f(h0.x);
    acc.y += e0 * bf2f(h0.y);
    acc.z += e0 * bf2f(h0.z);
    acc.w += e0 * bf2f(h0.w);
  }
  float inv = 1.f / (den + EPS_F);         // deg==0: acc=0 -> out=0
  *(f32x4*)(out + (size_t)n * NHD + lane * 4) = acc * inv;
}

extern "C" void kernel_launch(void* const* d_in, const int* in_sizes, int n_in,
                              void* d_out, int out_size, void* d_ws, size_t ws_size,
                              hipStream_t stream) {
  const float* x  = (const float*)d_in[0];
  const int*   ei = (const int*)d_in[1];
  const float* W  = (const float*)d_in[2];
  const float* a  = (const float*)d_in[3];
  float* out = (float*)d_out;

  // workspace layout (~33 MB, 16B-aligned blocks)
  unsigned short* hb  = (unsigned short*)d_ws;                 // 12,800,000 u16
  unsigned short* WbT = hb + (size_t)N_NODES * NHD;            // 131,072 u16
  float* s_src = (float*)(WbT + (size_t)NHD * IN_F);           // 400,000 f
  float* s_dst = s_src + (size_t)N_NODES * HEADS;              // 400,000 f
  int* deg    = (int*)(s_dst + (size_t)N_NODES * HEADS);       // 50,000
  int* cursor = deg + N_NODES;                                 // 50,000
  int* rowptr = cursor + N_NODES;                              // 50,001 (pad 50,008)
  int* bsum   = rowptr + 50008;                                // 196 (pad 256)
  int* edst   = bsum + 256;                                    // 800,000

  hipMemsetAsync(deg, 0, (size_t)N_NODES * sizeof(int), stream);
  k_cast_w<<<(NHD * IN_F + 255) / 256, 256, 0, stream>>>(W, WbT);
  k_gemm_mfma<<<(N_NODES + 63) / 64, 256, 0, stream>>>(x, WbT, hb);
  k_scores<<<(N_NODES * 64 + 255) / 256, 256, 0, stream>>>(hb, a, s_src, s_dst);
  k_hist<<<(N_EDGES + 255) / 256, 256, 0, stream>>>(ei, deg);
  k_bsum<<<N_SBLK, 256, 0, stream>>>(deg, bsum);
  k_scan_main<<<N_SBLK, 256, 0, stream>>>(deg, bsum, rowptr, cursor);
  k_fill<<<(N_EDGES + 255) / 256, 256, 0, stream>>>(ei, cursor, edst);
  k_aggr<<<(N_NODES * 64 + 255) / 256, 256, 0, stream>>>(rowptr, edst, s_src, s_dst, hb, out);
}